// Round 2
// baseline (106.945 us; speedup 1.0000x reference)
//
#include <hip/hip_runtime.h>

#define NB    4
#define DIN_  64
#define DP_   3
#define DOUT_ 64
#define KN    16
#define NPT   8192
#define CPAD  264   // 256 c-entries + 8 bf16 pad -> 528B rows, 16B-aligned, bank-spread
#define CTOT  256

typedef __attribute__((ext_vector_type(8))) short short8;
typedef __attribute__((ext_vector_type(4))) float v4f;

__device__ __forceinline__ float bf2f(unsigned short u) {
    unsigned int x = ((unsigned int)u) << 16;
    float f; __builtin_memcpy(&f, &x, 4); return f;
}
__device__ __forceinline__ unsigned short f2bf(float f) {
    unsigned int x; __builtin_memcpy(&x, &f, 4);
    x += 0x7fffu + ((x >> 16) & 1u);   // RNE
    return (unsigned short)(x >> 16);
}

// features fp32 [B][64][N] -> ft bf16 [B][N][64] (contiguous 128B-per-neighbor gathers)
__global__ void k_transpose_feat(const float* __restrict__ feat,
                                 unsigned short* __restrict__ ft) {
    __shared__ float tile[64][65];
    int blk  = blockIdx.x;
    int b    = blk >> 7;            // NPT/64 = 128 tiles per batch
    int n0   = (blk & 127) << 6;
    int lane = threadIdx.x & 63;
    int w    = threadIdx.x >> 6;
#pragma unroll
    for (int r = 0; r < 16; ++r) {
        int i = (r << 2) | w;
        tile[i][lane] = feat[(b*DIN_ + i)*NPT + n0 + lane];
    }
    __syncthreads();
#pragma unroll
    for (int r = 0; r < 16; ++r) {
        int n = (r << 2) | w;
        ft[((size_t)(b*NPT + n0 + n))*DIN_ + lane] = f2bf(tile[lane][n]);
    }
}

// positions fp32 [B][3][N] -> pt [B*N] float4 = (x,y,z,1.0)  (w=1 drives the S-row)
__global__ void k_transpose_pos(const float* __restrict__ pos,
                                float4* __restrict__ pt) {
    int t = blockIdx.x*256 + threadIdx.x;   // over NB*NPT
    int b = t >> 13, n = t & 8191;
    float4 v;
    v.x = pos[(b*3 + 0)*NPT + n];
    v.y = pos[(b*3 + 1)*NPT + n];
    v.z = pos[(b*3 + 2)*NPT + n];
    v.w = 1.0f;
    pt[t] = v;
}

// Fused: stage-1 gather+contract-K (fp32, wave-per-point) -> Xt LDS (bf16)
//        epilogue [64 x 256] x [256 x 32] GEMM via mfma_f32_16x16x32_bf16
template<bool USE_WS>
__global__ __launch_bounds__(256, 3) void k_main(
    const float*          __restrict__ feat,
    const float*          __restrict__ pos,
    const int*            __restrict__ nbr,
    const float*          __restrict__ theta,
    const float*          __restrict__ pbias,
    const float*          __restrict__ fbias,
    const unsigned short* __restrict__ ft,
    const float4*         __restrict__ pt,
    float*                __restrict__ out)
{
    __shared__ __align__(16) unsigned short Tt[64*CPAD];  // [o][c], c = p*64+i (c>=192: pbias)
    __shared__ __align__(16) unsigned short Xt[32*CPAD];  // [q][c]

    const int tid  = threadIdx.x;
    const int lane = tid & 63;
    const int w    = tid >> 6;
    const int j16  = lane & 15;   // i-chunk (stage1) / m,n index (mfma)
    const int kg   = lane >> 4;   // k-group (stage1) / quad (mfma)

    // combined theta: T flat [c][o] == concat(theta[p][i][o], pbias[i][o]) exactly
    for (int idx = tid; idx < 16384; idx += 256) {
        int c = idx >> 6, o = idx & 63;
        Tt[o*CPAD + c] = f2bf((c < 192) ? theta[idx] : pbias[idx - 12288]);
    }
    __syncthreads();

    const int base = blockIdx.x << 5;   // 32 points, never crosses a batch (8192%32==0)
    const int b    = base >> 13;
    const int nb0  = base & 8191;

    // ---------- stage 1: each wave computes X for its 8 points ----------
    for (int s = 0; s < 8; ++s) {
        const int q = (w << 3) + s;
        const int n = nb0 + q;
        float4 pc;
        if (USE_WS) pc = pt[b*NPT + n];
        else {
            pc.x = pos[(b*3+0)*NPT + n];
            pc.y = pos[(b*3+1)*NPT + n];
            pc.z = pos[(b*3+2)*NPT + n];
            pc.w = 1.0f;
        }
        int idxs[4];
#pragma unroll
        for (int t = 0; t < 4; ++t)
            idxs[t] = nbr[(b*KN + (kg<<2) + t)*NPT + n];

        float acc[4][4];
#pragma unroll
        for (int p = 0; p < 4; ++p)
#pragma unroll
            for (int j = 0; j < 4; ++j) acc[p][j] = 0.f;

#pragma unroll
        for (int t = 0; t < 4; ++t) {
            const int id = idxs[t];
            float4 pg; float f[4];
            if (USE_WS) {
                pg = pt[b*NPT + id];
                ushort4 fr = *reinterpret_cast<const ushort4*>(
                    ft + (((size_t)(b*NPT + id)) << 6) + (j16 << 2));
                f[0]=bf2f(fr.x); f[1]=bf2f(fr.y); f[2]=bf2f(fr.z); f[3]=bf2f(fr.w);
            } else {
                pg.x = pos[(b*3+0)*NPT + id];
                pg.y = pos[(b*3+1)*NPT + id];
                pg.z = pos[(b*3+2)*NPT + id];
                pg.w = 1.0f;
#pragma unroll
                for (int j = 0; j < 4; ++j)
                    f[j] = feat[(b*DIN_ + (j16<<2) + j)*NPT + id];
            }
            const float wgt[4] = {pg.x, pg.y, pg.z, pg.w};
#pragma unroll
            for (int p = 0; p < 4; ++p)
#pragma unroll
                for (int j = 0; j < 4; ++j)
                    acc[p][j] += wgt[p] * f[j];
        }
        // M_p = sum(pg_p f) - pc_p * S ; pc uniform per point -> commutes with lane-sum
        const float pcv[3] = {pc.x, pc.y, pc.z};
#pragma unroll
        for (int p = 0; p < 3; ++p)
#pragma unroll
            for (int j = 0; j < 4; ++j)
                acc[p][j] -= pcv[p] * acc[3][j];
        // butterfly over the 4 k-groups (lane bits 4,5)
#pragma unroll
        for (int mask = 16; mask <= 32; mask <<= 1)
#pragma unroll
            for (int p = 0; p < 4; ++p)
#pragma unroll
                for (int j = 0; j < 4; ++j)
                    acc[p][j] += __shfl_xor(acc[p][j], mask, 64);
        // replica kg writes p=kg slice: Xt[q][kg*64 + j16*4 .. +3]
        ushort4 pk;
        pk.x = f2bf(acc[kg][0]); pk.y = f2bf(acc[kg][1]);
        pk.z = f2bf(acc[kg][2]); pk.w = f2bf(acc[kg][3]);
        *reinterpret_cast<ushort4*>(&Xt[q*CPAD + (kg<<6) + (j16<<2)]) = pk;
    }
    __syncthreads();

    // ---------- epilogue: wave w -> o-tile [16w,16w+16), both 16-pt tiles ----------
    v4f acc0 = {0.f,0.f,0.f,0.f}, acc1 = {0.f,0.f,0.f,0.f};
    const int orow = (w << 4) + j16;        // A: m = lane&15
#pragma unroll
    for (int ks = 0; ks < 8; ++ks) {
        const int koff = (ks << 5) + (kg << 3);   // k = quad*8 + j
        short8 a  = *reinterpret_cast<const short8*>(&Tt[orow*CPAD + koff]);
        short8 b0 = *reinterpret_cast<const short8*>(&Xt[j16*CPAD + koff]);
        short8 b1 = *reinterpret_cast<const short8*>(&Xt[(16 + j16)*CPAD + koff]);
        acc0 = __builtin_amdgcn_mfma_f32_16x16x32_bf16(a, b0, acc0, 0, 0, 0);
        acc1 = __builtin_amdgcn_mfma_f32_16x16x32_bf16(a, b1, acc1, 0, 0, 0);
    }
    // C/D: col=lane&15 (point), row=quad*4+reg (o)
#pragma unroll
    for (int r = 0; r < 4; ++r) {
        const int o = (w << 4) + (kg << 2) + r;
        const float fb = fbias[o];
        const size_t rowoff = (size_t)(b*DOUT_ + o)*NPT + nb0;
        out[rowoff + j16]      = acc0[r] + fb;
        out[rowoff + 16 + j16] = acc1[r] + fb;
    }
}

extern "C" void kernel_launch(void* const* d_in, const int* in_sizes, int n_in,
                              void* d_out, int out_size, void* d_ws, size_t ws_size,
                              hipStream_t stream) {
    const float* feat  = (const float*)d_in[0];
    const float* pos   = (const float*)d_in[1];
    const int*   nbr   = (const int*)d_in[2];
    const float* theta = (const float*)d_in[3];
    const float* pbias = (const float*)d_in[4];
    const float* fbias = (const float*)d_in[5];
    float* out = (float*)d_out;

    const size_t ft_bytes = (size_t)NB*NPT*DIN_*2;          // 4 MiB (bf16)
    const size_t pt_bytes = (size_t)NB*NPT*sizeof(float4);  // 512 KiB
    const int n_blocks = (NB*NPT)/32;                       // 1024

    if (ws_size >= ft_bytes + pt_bytes) {
        unsigned short* ft = (unsigned short*)d_ws;
        float4* pt = (float4*)((char*)d_ws + ft_bytes);
        k_transpose_feat<<<NB*(NPT/64), 256, 0, stream>>>(feat, ft);
        k_transpose_pos<<<(NB*NPT)/256, 256, 0, stream>>>(pos, pt);
        k_main<true><<<n_blocks, 256, 0, stream>>>(feat, pos, nbr, theta, pbias, fbias,
                                                   ft, pt, out);
    } else {
        k_main<false><<<n_blocks, 256, 0, stream>>>(feat, pos, nbr, theta, pbias, fbias,
                                                    (const unsigned short*)feat,
                                                    (const float4*)feat, out);
    }
}

// Round 3
// 89.253 us; speedup vs baseline: 1.1982x; 1.1982x over previous
//
#include <hip/hip_runtime.h>

#define NB    4
#define DIN_  64
#define DOUT_ 64
#define KN    16
#define NPT   8192
#define CPAD  264   // 256 c-entries + 8 pad shorts; rows 528B (16B-aligned)

typedef __attribute__((ext_vector_type(8))) short short8;
typedef __attribute__((ext_vector_type(4))) float v4f;

__device__ __forceinline__ float bf2f(unsigned short u) {
    unsigned int x = ((unsigned int)u) << 16;
    float f; __builtin_memcpy(&f, &x, 4); return f;
}
__device__ __forceinline__ unsigned short f2bf(float f) {
    unsigned int x; __builtin_memcpy(&x, &f, 4);
    x += 0x7fffu + ((x >> 16) & 1u);   // RNE
    return (unsigned short)(x >> 16);
}

// ---------- prep: 3 jobs in one dispatch ----------
// blocks [0,512):  feat fp32 [B][64][N] -> ft bf16 [B][N][64]
// blocks [512,640): pos fp32 [B][3][N]  -> pt float4 (x,y,z,1)
// blocks [640,648): theta/pbias -> tbf bf16 [64][256]  (Tt[o][c], c=p*64+i; c>=192 -> pbias)
__global__ void k_prep(const float* __restrict__ feat, const float* __restrict__ pos,
                       const float* __restrict__ theta, const float* __restrict__ pbias,
                       unsigned short* __restrict__ ft, float4* __restrict__ pt,
                       unsigned short* __restrict__ tbf) {
    __shared__ float tile[64][65];
    const int bid = blockIdx.x;
    if (bid < 512) {
        int b = bid >> 7, n0 = (bid & 127) << 6;
        int lane = threadIdx.x & 63, w = threadIdx.x >> 6;
#pragma unroll
        for (int r = 0; r < 16; ++r) {
            int i = (r << 2) | w;
            tile[i][lane] = feat[(b*DIN_ + i)*NPT + n0 + lane];
        }
        __syncthreads();
#pragma unroll
        for (int r = 0; r < 16; ++r) {
            int n = (r << 2) | w;
            ft[((size_t)(b*NPT + n0 + n))*DIN_ + lane] = f2bf(tile[lane][n]);
        }
    } else if (bid < 640) {
        int t = (bid - 512)*256 + threadIdx.x;   // 0..32767
        int b = t >> 13, n = t & 8191;
        float4 v;
        v.x = pos[(b*3 + 0)*NPT + n];
        v.y = pos[(b*3 + 1)*NPT + n];
        v.z = pos[(b*3 + 2)*NPT + n];
        v.w = 1.0f;
        pt[t] = v;
    } else {
        int e = (bid - 640)*256 + threadIdx.x;   // 0..2047
        int o = e >> 5, g = e & 31;
        short8 u;
#pragma unroll
        for (int j = 0; j < 8; ++j) {
            int c = g*8 + j;
            float v = (c < 192) ? theta[c*64 + o] : pbias[(c - 192)*64 + o];
            u[j] = (short)f2bf(v);
        }
        *reinterpret_cast<short8*>(tbf + o*256 + g*8) = u;   // 16B aligned
    }
}

// ---------- main: gather+contract (no cross-lane) -> Xt LDS -> MFMA epilogue ----------
template<bool USE_WS>
__global__ __launch_bounds__(256, 4) void k_main(
    const float*          __restrict__ feat,
    const float*          __restrict__ pos,
    const int*            __restrict__ nbr,
    const float*          __restrict__ theta,
    const float*          __restrict__ pbias,
    const float*          __restrict__ fbias,
    const unsigned short* __restrict__ ft,
    const float4*         __restrict__ pt,
    const unsigned short* __restrict__ tbf,
    float*                __restrict__ out)
{
    __shared__ __align__(16) unsigned short Xt[32*CPAD];  // 16896 B  [q][c]
    __shared__ int    nbs[KN*32];                         // 2048 B   [k][q]
    __shared__ float4 pcs[32];                            // 512 B

    const int tid  = threadIdx.x;
    const int lane = tid & 63;
    const int w    = tid >> 6;
    const int j16  = lane & 15;
    const int pt2  = lane >> 4;    // stage1: which of 4 points; epilogue: quad (kg)

    const int base = blockIdx.x << 5;   // 32 points/block; 8192%32==0 -> single batch
    const int b    = base >> 13;
    const int nb0  = base & 8191;

    // ---- cooperative preamble: nbr slab + center positions ----
#pragma unroll
    for (int r = 0; r < 2; ++r) {
        int idx = tid + (r << 8);            // 0..511
        int k = idx >> 5, c = idx & 31;
        nbs[idx] = nbr[(b*KN + k)*NPT + nb0 + c];
    }
    if (tid < 128) {
        if (USE_WS) {
            ((float*)pcs)[tid] = ((const float*)(pt + b*NPT + nb0))[tid];
        } else if (tid < 32) {
            int n = nb0 + tid;
            pcs[tid] = make_float4(pos[(b*3+0)*NPT + n], pos[(b*3+1)*NPT + n],
                                   pos[(b*3+2)*NPT + n], 1.0f);
        }
    }
    __syncthreads();

    const unsigned short* ftb = ft + (((size_t)b) << 19);   // b*NPT*64

    // ---- stage 1: 2 passes x 4 points per wave; lane owns (point, 4-feature chunk) ----
#pragma unroll
    for (int pass = 0; pass < 2; ++pass) {
        const int q = (w << 3) + (pass << 2) + pt2;
        const float4 pc = pcs[q];
        float acc[4][4];
#pragma unroll
        for (int p = 0; p < 4; ++p)
#pragma unroll
            for (int j = 0; j < 4; ++j) acc[p][j] = 0.f;

#pragma unroll 4
        for (int k = 0; k < KN; ++k) {
            const int id = nbs[(k << 5) + q];      // LDS broadcast (16 lanes share)
            float4 pg; float f[4];
            if (USE_WS) {
                pg = pt[b*NPT + id];
                ushort4 fr = *reinterpret_cast<const ushort4*>(
                    ftb + (((size_t)id) << 6) + (j16 << 2));
                f[0]=bf2f(fr.x); f[1]=bf2f(fr.y); f[2]=bf2f(fr.z); f[3]=bf2f(fr.w);
            } else {
                pg.x = pos[(b*3+0)*NPT + id];
                pg.y = pos[(b*3+1)*NPT + id];
                pg.z = pos[(b*3+2)*NPT + id];
                pg.w = 1.0f;
#pragma unroll
                for (int j = 0; j < 4; ++j)
                    f[j] = feat[(b*DIN_ + (j16<<2) + j)*NPT + id];
            }
#pragma unroll
            for (int j = 0; j < 4; ++j) {
                acc[0][j] += pg.x * f[j];
                acc[1][j] += pg.y * f[j];
                acc[2][j] += pg.z * f[j];
                acc[3][j] += f[j];
            }
        }
        // center correction: M_p -= pc_p * S
#pragma unroll
        for (int j = 0; j < 4; ++j) {
            acc[0][j] -= pc.x * acc[3][j];
            acc[1][j] -= pc.y * acc[3][j];
            acc[2][j] -= pc.z * acc[3][j];
        }
        // write X[q][c], c = p*64 + j16*4 + j  (bf16)
#pragma unroll
        for (int p = 0; p < 4; ++p) {
            ushort4 pk;
            pk.x = f2bf(acc[p][0]); pk.y = f2bf(acc[p][1]);
            pk.z = f2bf(acc[p][2]); pk.w = f2bf(acc[p][3]);
            *reinterpret_cast<ushort4*>(&Xt[q*CPAD + (p<<6) + (j16<<2)]) = pk;
        }
    }
    __syncthreads();

    // ---- epilogue: wave w -> o-rows [16w,16w+16); A-frags straight from L2-hot tbf ----
    const int kg   = pt2;                 // mfma quad
    const int orow = (w << 4) + j16;      // A: m = lane&15
    v4f acc0 = {0.f,0.f,0.f,0.f}, acc1 = {0.f,0.f,0.f,0.f};
#pragma unroll
    for (int ks = 0; ks < 8; ++ks) {
        const int koff = (ks << 5) + (kg << 3);   // k = quad*8 + j
        short8 a;
        if (USE_WS) {
            a = *reinterpret_cast<const short8*>(tbf + orow*256 + koff);
        } else {
#pragma unroll
            for (int j = 0; j < 8; ++j) {
                int c = koff + j;
                float v = (c < 192) ? theta[c*64 + orow] : pbias[(c - 192)*64 + orow];
                a[j] = (short)f2bf(v);
            }
        }
        short8 b0 = *reinterpret_cast<const short8*>(&Xt[j16*CPAD + koff]);
        short8 b1 = *reinterpret_cast<const short8*>(&Xt[(16 + j16)*CPAD + koff]);
        acc0 = __builtin_amdgcn_mfma_f32_16x16x32_bf16(a, b0, acc0, 0, 0, 0);
        acc1 = __builtin_amdgcn_mfma_f32_16x16x32_bf16(a, b1, acc1, 0, 0, 0);
    }
    // C/D: col=lane&15 (point), row=quad*4+reg (o)
#pragma unroll
    for (int r = 0; r < 4; ++r) {
        const int o = (w << 4) + (kg << 2) + r;
        const float fb = fbias[o];
        const size_t rowoff = (size_t)(b*DOUT_ + o)*NPT + nb0;
        out[rowoff + j16]      = acc0[r] + fb;
        out[rowoff + 16 + j16] = acc1[r] + fb;
    }
}

extern "C" void kernel_launch(void* const* d_in, const int* in_sizes, int n_in,
                              void* d_out, int out_size, void* d_ws, size_t ws_size,
                              hipStream_t stream) {
    const float* feat  = (const float*)d_in[0];
    const float* pos   = (const float*)d_in[1];
    const int*   nbr   = (const int*)d_in[2];
    const float* theta = (const float*)d_in[3];
    const float* pbias = (const float*)d_in[4];
    const float* fbias = (const float*)d_in[5];
    float* out = (float*)d_out;

    const size_t ft_bytes  = (size_t)NB*NPT*DIN_*2;          // 4 MiB
    const size_t pt_bytes  = (size_t)NB*NPT*sizeof(float4);  // 512 KiB
    const size_t tbf_bytes = (size_t)DOUT_*256*2;            // 32 KiB
    const int n_blocks = (NB*NPT)/32;                        // 1024

    if (ws_size >= ft_bytes + pt_bytes + tbf_bytes) {
        unsigned short* ft  = (unsigned short*)d_ws;
        float4*         pt  = (float4*)((char*)d_ws + ft_bytes);
        unsigned short* tbf = (unsigned short*)((char*)d_ws + ft_bytes + pt_bytes);
        k_prep<<<648, 256, 0, stream>>>(feat, pos, theta, pbias, ft, pt, tbf);
        k_main<true><<<n_blocks, 256, 0, stream>>>(feat, pos, nbr, theta, pbias, fbias,
                                                   ft, pt, tbf, out);
    } else {
        k_main<false><<<n_blocks, 256, 0, stream>>>(feat, pos, nbr, theta, pbias, fbias,
                                                    (const unsigned short*)feat,
                                                    (const float4*)feat,
                                                    (const unsigned short*)feat, out);
    }
}